// Round 4
// baseline (488.096 us; speedup 1.0000x reference)
//
#include <hip/hip_runtime.h>
#include <math.h>

// TriOut: z[L,L,Z] -> LN -> gated proj to C -> einsum('ilc,jlc->ijc') -> LN(C)
//         -> proj back to Z -> * sigmoid(zn@g_w+g_b)
// L=768, Z=128, C=32.  Output fp32 [L,L,Z].
//
// ws layout:
//   a_t  : bf16 [C][L*L]   ( 37,748,736 B)  a, c-major -> 32 batched A*A^T GEMMs
//   gate : bf16 [L*L][Z]   (150,994,944 B)  sigmoid(zn@g_w + g_b)
//   obuf : fp32 [C][L*L]   ( 75,497,472 B)  einsum result, c-major
//   wcat : bf16 [192][128] aliased onto obuf start (only live k0->k1, k2 clobbers)

#define LDIM 768
#define LL   (768 * 768)
#define ZD   128
#define CD   32

typedef __bf16 bf16x8 __attribute__((ext_vector_type(8)));
typedef float  f32x4  __attribute__((ext_vector_type(4)));

__device__ __forceinline__ ushort f2bf(float f) {
    __bf16 h = (__bf16)f;                      // RNE convert
    return __builtin_bit_cast(ushort, h);
}
__device__ __forceinline__ float bf2f(ushort u) {
    return __builtin_bit_cast(float, ((unsigned)u) << 16);
}
// fast sigmoid: v_exp_f32 + v_rcp_f32 (~1 ulp fp32 -- far below bf16 rounding)
__device__ __forceinline__ float sigm(float x) {
    return __builtin_amdgcn_rcpf(1.0f + __expf(-x));
}

// ---------------------------------------------------------------------------
// k0: pack [a_w ; ag_w ; g_w] -> bf16 wcat[192][128]   (runs once, 96 blocks)
// ---------------------------------------------------------------------------
__global__ __launch_bounds__(256) void k0_wconv(
    const float* __restrict__ aw, const float* __restrict__ agw,
    const float* __restrict__ gw, ushort* __restrict__ wcat)
{
    const int idx = blockIdx.x * 256 + threadIdx.x;
    if (idx >= 192 * ZD) return;
    const int ch = idx >> 7, k = idx & 127;
    const float v = (ch < 32) ? aw[ch * ZD + k]
                  : (ch < 64) ? agw[(ch - 32) * ZD + k]
                              : gw[(ch - 64) * ZD + k];
    wcat[idx] = f2bf(v);
}

// ---------------------------------------------------------------------------
// k1: per 64 rows of the flattened [L*L, Z] view:
//   LN(z) fp32 -> zn bf16 (LDS);  B-fragments read DIRECTLY from global wcat
//   (48 KB, L1/L2-hot; per-wave one full pass = 48 dwordx4/lane) -- no weight
//   LDS: kills the 8-way-conflict wl reads and drops LDS 69.6->17.4 KB for
//   ~4x block residency.
//   4 waves x (16 rows x 192 ch) via mfma_f32_16x16x32_bf16 (12 n-tiles x 4 k);
//   epilogue: a=(pa+ab)*sigm(pag+agb) -> a_t (c-major), sigm(g+gb) -> gate.
// ---------------------------------------------------------------------------
__global__ __launch_bounds__(256) void k1_ln_proj(
    const float* __restrict__ z, const float* __restrict__ nw, const float* __restrict__ nb,
    const ushort* __restrict__ wcat,
    const float* __restrict__ ab, const float* __restrict__ agb, const float* __restrict__ gb,
    ushort* __restrict__ a_t, ushort* __restrict__ gate)
{
    __shared__ ushort zn[64][136];   // pad 128->136: 16B-aligned rows

    const int tid = threadIdx.x;
    const size_t rowbase = (size_t)blockIdx.x * 64;

    // ---- LayerNorm: 4 threads/row, 32 elems each, fp32 ----
    {
        const int r = tid >> 2, seg = tid & 3;
        const float4* zp = (const float4*)(z + (rowbase + r) * ZD + seg * 32);
        float v[32];
        #pragma unroll
        for (int q = 0; q < 8; ++q) {
            const float4 t = zp[q];
            v[q * 4 + 0] = t.x; v[q * 4 + 1] = t.y;
            v[q * 4 + 2] = t.z; v[q * 4 + 3] = t.w;
        }
        float s = 0.f, ss = 0.f;
        #pragma unroll
        for (int e = 0; e < 32; ++e) { s += v[e]; ss += v[e] * v[e]; }
        s += __shfl_xor(s, 1); ss += __shfl_xor(ss, 1);
        s += __shfl_xor(s, 2); ss += __shfl_xor(ss, 2);
        const float mu  = s * (1.f / 128.f);
        const float var = ss * (1.f / 128.f) - mu * mu;
        const float rs  = rsqrtf(var + 1e-5f);
        union { ushort u[32]; uint4 q4[4]; } pk;
        #pragma unroll
        for (int e = 0; e < 32; ++e) {
            const int k = seg * 32 + e;
            pk.u[e] = f2bf((v[e] - mu) * rs * nw[k] + nb[k]);
        }
        #pragma unroll
        for (int q = 0; q < 4; ++q)
            *(uint4*)&zn[r][seg * 32 + q * 8] = pk.q4[q];
    }
    __syncthreads();

    // ---- MFMA: wave w -> rows w*16..+15, all 192 channels ----
    const int lane = tid & 63, wave = tid >> 6;
    const int fr = lane & 15, hi = lane >> 4;
    const int wrow = wave * 16;

    bf16x8 af[4];
    #pragma unroll
    for (int kk = 0; kk < 4; ++kk)
        af[kk] = *(const bf16x8*)&zn[wrow + fr][kk * 32 + hi * 8];

    f32x4 acc[12];
    #pragma unroll
    for (int n = 0; n < 12; ++n) acc[n] = (f32x4){0.f, 0.f, 0.f, 0.f};

    // B-frag source: row n*16+fr, cols kk*32+hi*8 .. +7  (16B, aligned)
    const ushort* wb = wcat + (size_t)fr * ZD + hi * 8;
    #pragma unroll
    for (int n = 0; n < 12; ++n)
        #pragma unroll
        for (int kk = 0; kk < 4; ++kk) {
            const bf16x8 bv = *(const bf16x8*)(wb + n * 16 * ZD + kk * 32);
            acc[n] = __builtin_amdgcn_mfma_f32_16x16x32_bf16(af[kk], bv, acc[n], 0, 0, 0);
        }

    // ---- epilogue: a * sigmoid(ag) -> a_t (c-major, 4 rows packed) ----
    const int orow = wrow + hi * 4;
    #pragma unroll
    for (int n = 0; n < 2; ++n) {
        const int ch = n * 16 + fr;
        const float abv = ab[ch], agbv = agb[ch];
        union { ushort u[4]; uint2 d; } pk;
        #pragma unroll
        for (int q = 0; q < 4; ++q)
            pk.u[q] = f2bf((acc[n][q] + abv) * sigm(acc[n + 2][q] + agbv));
        *(uint2*)&a_t[(size_t)ch * LL + rowbase + orow] = pk.d;
    }

    // ---- epilogue: sigmoid(g) -> LDS transpose -> coalesced gate writes ----
    ushort gv[8][4];
    #pragma unroll
    for (int n2 = 0; n2 < 8; ++n2) {
        const int gch = n2 * 16 + fr;
        const float gbv = gb[gch];
        #pragma unroll
        for (int q = 0; q < 4; ++q)
            gv[n2][q] = f2bf(sigm(acc[4 + n2][q] + gbv));
    }
    __syncthreads();                       // all waves done reading zn
    ushort* gl = &zn[0][0];                // reuse zn LDS as [64][136]
    #pragma unroll
    for (int n2 = 0; n2 < 8; ++n2)
        #pragma unroll
        for (int q = 0; q < 4; ++q)
            gl[(size_t)(orow + q) * 136 + n2 * 16 + fr] = gv[n2][q];
    __syncthreads();
    #pragma unroll
    for (int it = 0; it < 4; ++it) {
        const int idx = it * 256 + tid;    // uint4 index (1024 total)
        const int r = idx >> 4, cq = idx & 15;
        *(uint4*)&gate[(rowbase + r) * ZD + cq * 8] = *(const uint4*)&gl[(size_t)r * 136 + cq * 8];
    }
}

// ---------------------------------------------------------------------------
// k2: 32 batched GEMMs  O_c = M_c * M_c^T,  M_c = a_t[c] as [768][768] bf16.
// 64x64 tile, BK=32, 4 waves (each 32x32 quadrant = 2x2 mfma_f32_16x16x32_bf16).
// ---------------------------------------------------------------------------
__global__ __launch_bounds__(256) void k2_einsum(
    const ushort* __restrict__ a_t, float* __restrict__ obuf)
{
    __shared__ ushort As[2][64][32];
    __shared__ ushort Bs[2][64][32];

    const int tid = threadIdx.x;
    const int c  = blockIdx.z;
    const int i0 = blockIdx.y * 64, j0 = blockIdx.x * 64;
    const ushort* base = a_t + (size_t)c * LL;

    const int srow = tid >> 2, scol = (tid & 3) * 8;
    const ushort* gA = base + (size_t)(i0 + srow) * LDIM + scol;
    const ushort* gB = base + (size_t)(j0 + srow) * LDIM + scol;

    const int wave = tid >> 6, lane = tid & 63;
    const int wi = (wave >> 1) * 32, wj = (wave & 1) * 32;
    const int fr = lane & 15, k8 = (lane >> 4) * 8;

    f32x4 acc[2][2];
    #pragma unroll
    for (int m = 0; m < 2; ++m)
        #pragma unroll
        for (int n = 0; n < 2; ++n)
            acc[m][n] = (f32x4){0.f, 0.f, 0.f, 0.f};

    auto stage = [&](int b, int kc) {
        *(uint4*)&As[b][srow][scol] = *(const uint4*)(gA + kc * 32);
        *(uint4*)&Bs[b][srow][scol] = *(const uint4*)(gB + kc * 32);
    };

    stage(0, 0);
    __syncthreads();
    for (int kc = 0; kc < 24; ++kc) {
        const int cur = kc & 1;
        if (kc + 1 < 24) stage(cur ^ 1, kc + 1);

        bf16x8 av[2], bv[2];
        #pragma unroll
        for (int m = 0; m < 2; ++m)
            av[m] = *(const bf16x8*)&As[cur][wi + m * 16 + fr][k8];
        #pragma unroll
        for (int n = 0; n < 2; ++n)
            bv[n] = *(const bf16x8*)&Bs[cur][wj + n * 16 + fr][k8];

        #pragma unroll
        for (int m = 0; m < 2; ++m)
            #pragma unroll
            for (int n = 0; n < 2; ++n)
                acc[m][n] = __builtin_amdgcn_mfma_f32_16x16x32_bf16(
                    av[m], bv[n], acc[m][n], 0, 0, 0);
        __syncthreads();
    }

    float* ob = obuf + (size_t)c * LL;
    #pragma unroll
    for (int m = 0; m < 2; ++m)
        #pragma unroll
        for (int n = 0; n < 2; ++n)
            #pragma unroll
            for (int q = 0; q < 4; ++q) {
                const int row = i0 + wi + m * 16 + (lane >> 4) * 4 + q;
                const int col = j0 + wj + n * 16 + fr;
                ob[(size_t)row * LDIM + col] = acc[m][n][q];
            }
}

// ---------------------------------------------------------------------------
// k3: per 64 flat rows of [L*L, ...]:
//   gather obuf (c-major) -> LDS, LN over C=32 (affine) -> bf16 An[64][36],
//   o_w staged bf16 Bw[128][36]; wave w: rows w*16..+15 x 128 out = 8 MFMA
//   (single k-step, K=32); +o_b -> fp32 Res (aliased over gather buf);
//   final: Res * gate -> out, fully coalesced float4.
// ---------------------------------------------------------------------------
__global__ __launch_bounds__(256) void k3_out(
    const float* __restrict__ obuf,
    const float* __restrict__ onw, const float* __restrict__ onb,
    const float* __restrict__ ow,  const float* __restrict__ obias,
    const ushort* __restrict__ gate, float* __restrict__ out)
{
    __shared__ union { float Ol[64][40]; float Res[64][132]; } u;
    __shared__ ushort An[64][36];
    __shared__ ushort Bw[128][36];

    const int tid = threadIdx.x;
    const size_t rowbase = (size_t)blockIdx.x * 64;

    // ---- gather obuf: wave cg loads channels cg*8..+7 for all 64 rows ----
    {
        const int jj = tid & 63, cg = tid >> 6;
        const size_t off = rowbase + jj;
        #pragma unroll
        for (int cc = 0; cc < 8; ++cc) {
            const int ch = cg * 8 + cc;
            u.Ol[jj][ch] = obuf[(size_t)ch * LL + off];
        }
    }
    // ---- stage o_w -> bf16 Bw: thread t -> row t>>1, 16-ch half t&1 ----
    {
        const int r = tid >> 1, h = tid & 1;
        const float* src = ow + r * CD + h * 16;
        union { ushort us[16]; uint4 q[2]; } pk;
        #pragma unroll
        for (int e = 0; e < 16; ++e) pk.us[e] = f2bf(src[e]);
        *(uint4*)&Bw[r][h * 16]     = pk.q[0];
        *(uint4*)&Bw[r][h * 16 + 8] = pk.q[1];
    }
    __syncthreads();

    // ---- LN over C=32: 4 threads/row, 8 ch each, affine -> bf16 An ----
    {
        const int r = tid >> 2, seg = tid & 3;
        float v[8];
        #pragma unroll
        for (int e = 0; e < 8; ++e) v[e] = u.Ol[r][seg * 8 + e];
        float s = 0.f, ss = 0.f;
        #pragma unroll
        for (int e = 0; e < 8; ++e) { s += v[e]; ss += v[e] * v[e]; }
        s += __shfl_xor(s, 1); ss += __shfl_xor(ss, 1);
        s += __shfl_xor(s, 2); ss += __shfl_xor(ss, 2);
        const float mu  = s * (1.f / 32.f);
        const float var = ss * (1.f / 32.f) - mu * mu;
        const float rs  = rsqrtf(var + 1e-5f);
        union { ushort us[8]; uint4 q; } pk;
        #pragma unroll
        for (int e = 0; e < 8; ++e) {
            const int c = seg * 8 + e;
            pk.us[e] = f2bf((v[e] - mu) * rs * onw[c] + onb[c]);
        }
        *(uint4*)&An[r][seg * 8] = pk.q;
    }
    __syncthreads();   // An/Bw ready; Ol dead beyond this point

    // ---- MFMA: wave w -> rows w*16..+15, 128 outputs, single k-step ----
    const int lane = tid & 63, wave = tid >> 6;
    const int fr = lane & 15, hi = lane >> 4;
    const int wrow = wave * 16;

    const bf16x8 af = *(const bf16x8*)&An[wrow + fr][hi * 8];
    f32x4 acc[8];
    #pragma unroll
    for (int n = 0; n < 8; ++n) {
        const bf16x8 bv = *(const bf16x8*)&Bw[n * 16 + fr][hi * 8];
        acc[n] = __builtin_amdgcn_mfma_f32_16x16x32_bf16(
            af, bv, (f32x4){0.f, 0.f, 0.f, 0.f}, 0, 0, 0);
    }

    // ---- +bias -> Res (aliases dead Ol) ----
    #pragma unroll
    for (int n = 0; n < 8; ++n) {
        const int ch = n * 16 + fr;
        const float obv = obias[ch];
        #pragma unroll
        for (int q = 0; q < 4; ++q)
            u.Res[wrow + hi * 4 + q][ch] = acc[n][q] + obv;
    }
    __syncthreads();

    // ---- Res * gate -> out, coalesced ----
    #pragma unroll
    for (int it = 0; it < 8; ++it) {
        const int idx = it * 256 + tid;          // 2048 float4 chunks
        const int r = idx >> 5, cq = (idx & 31) * 4;
        float4 v4 = *(const float4*)&u.Res[r][cq];
        union { uint2 d; ushort us[4]; } g;
        g.d = *(const uint2*)&gate[(rowbase + r) * ZD + cq];
        v4.x *= bf2f(g.us[0]); v4.y *= bf2f(g.us[1]);
        v4.z *= bf2f(g.us[2]); v4.w *= bf2f(g.us[3]);
        *(float4*)&out[(rowbase + r) * ZD + cq] = v4;
    }
}

extern "C" void kernel_launch(void* const* d_in, const int* in_sizes, int n_in,
                              void* d_out, int out_size, void* d_ws, size_t ws_size,
                              hipStream_t stream) {
    (void)in_sizes; (void)n_in; (void)out_size; (void)ws_size;
    const float* z   = (const float*)d_in[0];
    const float* nw  = (const float*)d_in[1];
    const float* nb  = (const float*)d_in[2];
    const float* onw = (const float*)d_in[3];
    const float* onb = (const float*)d_in[4];
    const float* aw  = (const float*)d_in[5];
    const float* ab  = (const float*)d_in[6];
    const float* agw = (const float*)d_in[7];
    const float* agb = (const float*)d_in[8];
    const float* gw  = (const float*)d_in[9];
    const float* gb  = (const float*)d_in[10];
    const float* ow  = (const float*)d_in[11];
    const float* ob  = (const float*)d_in[12];

    char* ws = (char*)d_ws;
    ushort* a_t  = (ushort*)ws;                                   // 37,748,736 B
    ushort* gate = (ushort*)(ws + 37748736);                      // 150,994,944 B
    float*  obuf = (float*)(ws + 37748736 + 150994944);           // 75,497,472 B
    ushort* wcat = (ushort*)obuf;  // aliased: live only k0->k1, k2 clobbers

    k0_wconv<<<96, 256, 0, stream>>>(aw, agw, gw, wcat);
    k1_ln_proj<<<LL / 64, 256, 0, stream>>>(z, nw, nb, wcat, ab, agb, gb,
                                            a_t, gate);
    k2_einsum<<<dim3(12, 12, 32), 256, 0, stream>>>(a_t, obuf);
    k3_out<<<LL / 64, 256, 0, stream>>>(obuf, onw, onb, ow, ob, gate,
                                        (float*)d_out);
}

// Round 5
// 365.539 us; speedup vs baseline: 1.3353x; 1.3353x over previous
//
#include <hip/hip_runtime.h>
#include <math.h>

// TriOut: z[L,L,Z] -> LN -> gated proj to C -> einsum('ilc,jlc->ijc') -> LN(C)
//         -> proj back to Z -> * sigmoid(zn@g_w+g_b)
// L=768, Z=128, C=32.  Output fp32 [L,L,Z].
//
// ws layout:
//   a_t  : bf16 [C][L*L]   ( 37,748,736 B)  a, c-major -> 32 batched A*A^T GEMMs
//   gate : bf16 [L*L][Z]   (150,994,944 B)  sigmoid(zn@g_w + g_b)
//   obuf : fp32 [C][L*L]   ( 75,497,472 B)  einsum result, c-major
//   wfrag: bf16 frag-ordered [12*4][64][8] aliased onto obuf start (48 KB;
//          live only k0->k1, k2 clobbers)

#define LDIM 768
#define LL   (768 * 768)
#define ZD   128
#define CD   32

typedef __bf16 bf16x8 __attribute__((ext_vector_type(8)));
typedef float  f32x4  __attribute__((ext_vector_type(4)));

__device__ __forceinline__ ushort f2bf(float f) {
    __bf16 h = (__bf16)f;                      // RNE convert
    return __builtin_bit_cast(ushort, h);
}
__device__ __forceinline__ float bf2f(ushort u) {
    return __builtin_bit_cast(float, ((unsigned)u) << 16);
}
// fast sigmoid: v_exp_f32 + v_rcp_f32 (~1 ulp fp32 -- far below bf16 rounding)
__device__ __forceinline__ float sigm(float x) {
    return __builtin_amdgcn_rcpf(1.0f + __expf(-x));
}

// ---------------------------------------------------------------------------
// k0: pack [a_w ; ag_w ; g_w] -> bf16 wfrag in MFMA B-FRAGMENT ORDER:
//   frag f = n*4+kk, lane l = fr + 16*hi:
//     wfrag[f*64 + l][j] = W[n*16+fr][kk*32 + hi*8 + j],  j=0..7
//   so k1's per-lane load is base + l*16B -> fully coalesced 1KB bursts.
// ---------------------------------------------------------------------------
__global__ __launch_bounds__(256) void k0_wfrag(
    const float* __restrict__ aw, const float* __restrict__ agw,
    const float* __restrict__ gw, ushort* __restrict__ wfrag)
{
    const int f = blockIdx.x * 256 + threadIdx.x;     // 3072 frags
    if (f >= 12 * 4 * 64) return;
    const int n4 = f >> 6, lane = f & 63;
    const int n = n4 >> 2, kk = n4 & 3;
    const int fr = lane & 15, hi = lane >> 4;
    const int ch = n * 16 + fr;
    const int k0 = kk * 32 + hi * 8;
    const float* src = (ch < 32) ? (aw + ch * ZD)
                     : (ch < 64) ? (agw + (ch - 32) * ZD)
                                 : (gw + (ch - 64) * ZD);
    union { ushort us[8]; uint4 q; } pk;
    #pragma unroll
    for (int j = 0; j < 8; ++j) pk.us[j] = f2bf(src[k0 + j]);
    *(uint4*)&wfrag[(size_t)f * 8] = pk.q;
}

// ---------------------------------------------------------------------------
// k1: per 64 rows of the flattened [L*L, Z] view:
//   LN(z) fp32 -> zn bf16 (LDS);  B-fragments loaded from global wfrag
//   (frag-ordered -> coalesced 1KB/instr, L1/L2-hot).  LDS = zn only (17.4 KB).
//   4 waves x (16 rows x 192 ch) via mfma_f32_16x16x32_bf16 (12 n-tiles x 4 k);
//   epilogue: a=(pa+ab)*sigm(pag+agb) -> a_t (c-major), sigm(g+gb) -> gate.
// ---------------------------------------------------------------------------
__global__ __launch_bounds__(256) void k1_ln_proj(
    const float* __restrict__ z, const float* __restrict__ nw, const float* __restrict__ nb,
    const ushort* __restrict__ wfrag,
    const float* __restrict__ ab, const float* __restrict__ agb, const float* __restrict__ gb,
    ushort* __restrict__ a_t, ushort* __restrict__ gate)
{
    __shared__ ushort zn[64][136];   // pad 128->136: 16B-aligned rows

    const int tid = threadIdx.x;
    const size_t rowbase = (size_t)blockIdx.x * 64;

    // ---- LayerNorm: 4 threads/row, 32 elems each, fp32 ----
    {
        const int r = tid >> 2, seg = tid & 3;
        const float4* zp = (const float4*)(z + (rowbase + r) * ZD + seg * 32);
        float v[32];
        #pragma unroll
        for (int q = 0; q < 8; ++q) {
            const float4 t = zp[q];
            v[q * 4 + 0] = t.x; v[q * 4 + 1] = t.y;
            v[q * 4 + 2] = t.z; v[q * 4 + 3] = t.w;
        }
        float s = 0.f, ss = 0.f;
        #pragma unroll
        for (int e = 0; e < 32; ++e) { s += v[e]; ss += v[e] * v[e]; }
        s += __shfl_xor(s, 1); ss += __shfl_xor(ss, 1);
        s += __shfl_xor(s, 2); ss += __shfl_xor(ss, 2);
        const float mu  = s * (1.f / 128.f);
        const float var = ss * (1.f / 128.f) - mu * mu;
        const float rs  = rsqrtf(var + 1e-5f);
        union { ushort u[32]; uint4 q4[4]; } pk;
        #pragma unroll
        for (int e = 0; e < 32; ++e) {
            const int k = seg * 32 + e;
            pk.u[e] = f2bf((v[e] - mu) * rs * nw[k] + nb[k]);
        }
        #pragma unroll
        for (int q = 0; q < 4; ++q)
            *(uint4*)&zn[r][seg * 32 + q * 8] = pk.q4[q];
    }
    __syncthreads();

    // ---- MFMA: wave w -> rows w*16..+15, all 192 channels ----
    const int lane = tid & 63, wave = tid >> 6;
    const int fr = lane & 15, hi = lane >> 4;
    const int wrow = wave * 16;

    bf16x8 af[4];
    #pragma unroll
    for (int kk = 0; kk < 4; ++kk)
        af[kk] = *(const bf16x8*)&zn[wrow + fr][kk * 32 + hi * 8];

    f32x4 acc[12];
    #pragma unroll
    for (int n = 0; n < 12; ++n) acc[n] = (f32x4){0.f, 0.f, 0.f, 0.f};

    // B-frags: coalesced -- lane l reads wfrag + (f*64 + l)*8 ushorts (16B)
    const ushort* wb = wfrag + (size_t)lane * 8;
    #pragma unroll
    for (int n = 0; n < 12; ++n)
        #pragma unroll
        for (int kk = 0; kk < 4; ++kk) {
            const bf16x8 bv = *(const bf16x8*)(wb + (size_t)(n * 4 + kk) * 512);
            acc[n] = __builtin_amdgcn_mfma_f32_16x16x32_bf16(af[kk], bv, acc[n], 0, 0, 0);
        }

    // ---- epilogue: a * sigmoid(ag) -> a_t (c-major, 4 rows packed) ----
    const int orow = wrow + hi * 4;
    #pragma unroll
    for (int n = 0; n < 2; ++n) {
        const int ch = n * 16 + fr;
        const float abv = ab[ch], agbv = agb[ch];
        union { ushort u[4]; uint2 d; } pk;
        #pragma unroll
        for (int q = 0; q < 4; ++q)
            pk.u[q] = f2bf((acc[n][q] + abv) * sigm(acc[n + 2][q] + agbv));
        *(uint2*)&a_t[(size_t)ch * LL + rowbase + orow] = pk.d;
    }

    // ---- epilogue: sigmoid(g) -> LDS transpose -> coalesced gate writes ----
    ushort gv[8][4];
    #pragma unroll
    for (int n2 = 0; n2 < 8; ++n2) {
        const int gch = n2 * 16 + fr;
        const float gbv = gb[gch];
        #pragma unroll
        for (int q = 0; q < 4; ++q)
            gv[n2][q] = f2bf(sigm(acc[4 + n2][q] + gbv));
    }
    __syncthreads();                       // all waves done reading zn
    ushort* gl = &zn[0][0];                // reuse zn LDS as [64][136]
    #pragma unroll
    for (int n2 = 0; n2 < 8; ++n2)
        #pragma unroll
        for (int q = 0; q < 4; ++q)
            gl[(size_t)(orow + q) * 136 + n2 * 16 + fr] = gv[n2][q];
    __syncthreads();
    #pragma unroll
    for (int it = 0; it < 4; ++it) {
        const int idx = it * 256 + tid;    // uint4 index (1024 total)
        const int r = idx >> 4, cq = idx & 15;
        *(uint4*)&gate[(rowbase + r) * ZD + cq * 8] = *(const uint4*)&gl[(size_t)r * 136 + cq * 8];
    }
}

// ---------------------------------------------------------------------------
// k2: 32 batched GEMMs  O_c = M_c * M_c^T,  M_c = a_t[c] as [768][768] bf16.
// 64x64 tile, BK=32, 4 waves (each 32x32 quadrant = 2x2 mfma_f32_16x16x32_bf16).
// ---------------------------------------------------------------------------
__global__ __launch_bounds__(256) void k2_einsum(
    const ushort* __restrict__ a_t, float* __restrict__ obuf)
{
    __shared__ ushort As[2][64][32];
    __shared__ ushort Bs[2][64][32];

    const int tid = threadIdx.x;
    const int c  = blockIdx.z;
    const int i0 = blockIdx.y * 64, j0 = blockIdx.x * 64;
    const ushort* base = a_t + (size_t)c * LL;

    const int srow = tid >> 2, scol = (tid & 3) * 8;
    const ushort* gA = base + (size_t)(i0 + srow) * LDIM + scol;
    const ushort* gB = base + (size_t)(j0 + srow) * LDIM + scol;

    const int wave = tid >> 6, lane = tid & 63;
    const int wi = (wave >> 1) * 32, wj = (wave & 1) * 32;
    const int fr = lane & 15, k8 = (lane >> 4) * 8;

    f32x4 acc[2][2];
    #pragma unroll
    for (int m = 0; m < 2; ++m)
        #pragma unroll
        for (int n = 0; n < 2; ++n)
            acc[m][n] = (f32x4){0.f, 0.f, 0.f, 0.f};

    auto stage = [&](int b, int kc) {
        *(uint4*)&As[b][srow][scol] = *(const uint4*)(gA + kc * 32);
        *(uint4*)&Bs[b][srow][scol] = *(const uint4*)(gB + kc * 32);
    };

    stage(0, 0);
    __syncthreads();
    for (int kc = 0; kc < 24; ++kc) {
        const int cur = kc & 1;
        if (kc + 1 < 24) stage(cur ^ 1, kc + 1);

        bf16x8 av[2], bv[2];
        #pragma unroll
        for (int m = 0; m < 2; ++m)
            av[m] = *(const bf16x8*)&As[cur][wi + m * 16 + fr][k8];
        #pragma unroll
        for (int n = 0; n < 2; ++n)
            bv[n] = *(const bf16x8*)&Bs[cur][wj + n * 16 + fr][k8];

        #pragma unroll
        for (int m = 0; m < 2; ++m)
            #pragma unroll
            for (int n = 0; n < 2; ++n)
                acc[m][n] = __builtin_amdgcn_mfma_f32_16x16x32_bf16(
                    av[m], bv[n], acc[m][n], 0, 0, 0);
        __syncthreads();
    }

    float* ob = obuf + (size_t)c * LL;
    #pragma unroll
    for (int m = 0; m < 2; ++m)
        #pragma unroll
        for (int n = 0; n < 2; ++n)
            #pragma unroll
            for (int q = 0; q < 4; ++q) {
                const int row = i0 + wi + m * 16 + (lane >> 4) * 4 + q;
                const int col = j0 + wj + n * 16 + fr;
                ob[(size_t)row * LDIM + col] = acc[m][n][q];
            }
}

// ---------------------------------------------------------------------------
// k3: per 64 flat rows of [L*L, ...]:
//   gather obuf (c-major) -> LDS, LN over C=32 (affine) -> bf16 An[64][36],
//   o_w staged bf16 Bw[128][36]; wave w: rows w*16..+15 x 128 out = 8 MFMA
//   (single k-step, K=32); +o_b -> fp32 Res (aliased over gather buf);
//   final: Res * gate -> out, fully coalesced float4.
// ---------------------------------------------------------------------------
__global__ __launch_bounds__(256) void k3_out(
    const float* __restrict__ obuf,
    const float* __restrict__ onw, const float* __restrict__ onb,
    const float* __restrict__ ow,  const float* __restrict__ obias,
    const ushort* __restrict__ gate, float* __restrict__ out)
{
    __shared__ union { float Ol[64][40]; float Res[64][132]; } u;
    __shared__ ushort An[64][36];
    __shared__ ushort Bw[128][36];

    const int tid = threadIdx.x;
    const size_t rowbase = (size_t)blockIdx.x * 64;

    // ---- gather obuf: wave cg loads channels cg*8..+7 for all 64 rows ----
    {
        const int jj = tid & 63, cg = tid >> 6;
        const size_t off = rowbase + jj;
        #pragma unroll
        for (int cc = 0; cc < 8; ++cc) {
            const int ch = cg * 8 + cc;
            u.Ol[jj][ch] = obuf[(size_t)ch * LL + off];
        }
    }
    // ---- stage o_w -> bf16 Bw: thread t -> row t>>1, 16-ch half t&1 ----
    {
        const int r = tid >> 1, h = tid & 1;
        const float* src = ow + r * CD + h * 16;
        union { ushort us[16]; uint4 q[2]; } pk;
        #pragma unroll
        for (int e = 0; e < 16; ++e) pk.us[e] = f2bf(src[e]);
        *(uint4*)&Bw[r][h * 16]     = pk.q[0];
        *(uint4*)&Bw[r][h * 16 + 8] = pk.q[1];
    }
    __syncthreads();

    // ---- LN over C=32: 4 threads/row, 8 ch each, affine -> bf16 An ----
    {
        const int r = tid >> 2, seg = tid & 3;
        float v[8];
        #pragma unroll
        for (int e = 0; e < 8; ++e) v[e] = u.Ol[r][seg * 8 + e];
        float s = 0.f, ss = 0.f;
        #pragma unroll
        for (int e = 0; e < 8; ++e) { s += v[e]; ss += v[e] * v[e]; }
        s += __shfl_xor(s, 1); ss += __shfl_xor(ss, 1);
        s += __shfl_xor(s, 2); ss += __shfl_xor(ss, 2);
        const float mu  = s * (1.f / 32.f);
        const float var = ss * (1.f / 32.f) - mu * mu;
        const float rs  = rsqrtf(var + 1e-5f);
        union { ushort us[8]; uint4 q; } pk;
        #pragma unroll
        for (int e = 0; e < 8; ++e) {
            const int c = seg * 8 + e;
            pk.us[e] = f2bf((v[e] - mu) * rs * onw[c] + onb[c]);
        }
        *(uint4*)&An[r][seg * 8] = pk.q;
    }
    __syncthreads();   // An/Bw ready; Ol dead beyond this point

    // ---- MFMA: wave w -> rows w*16..+15, 128 outputs, single k-step ----
    const int lane = tid & 63, wave = tid >> 6;
    const int fr = lane & 15, hi = lane >> 4;
    const int wrow = wave * 16;

    const bf16x8 af = *(const bf16x8*)&An[wrow + fr][hi * 8];
    f32x4 acc[8];
    #pragma unroll
    for (int n = 0; n < 8; ++n) {
        const bf16x8 bv = *(const bf16x8*)&Bw[n * 16 + fr][hi * 8];
        acc[n] = __builtin_amdgcn_mfma_f32_16x16x32_bf16(
            af, bv, (f32x4){0.f, 0.f, 0.f, 0.f}, 0, 0, 0);
    }

    // ---- +bias -> Res (aliases dead Ol) ----
    #pragma unroll
    for (int n = 0; n < 8; ++n) {
        const int ch = n * 16 + fr;
        const float obv = obias[ch];
        #pragma unroll
        for (int q = 0; q < 4; ++q)
            u.Res[wrow + hi * 4 + q][ch] = acc[n][q] + obv;
    }
    __syncthreads();

    // ---- Res * gate -> out, coalesced ----
    #pragma unroll
    for (int it = 0; it < 8; ++it) {
        const int idx = it * 256 + tid;          // 2048 float4 chunks
        const int r = idx >> 5, cq = (idx & 31) * 4;
        float4 v4 = *(const float4*)&u.Res[r][cq];
        union { uint2 d; ushort us[4]; } g;
        g.d = *(const uint2*)&gate[(rowbase + r) * ZD + cq];
        v4.x *= bf2f(g.us[0]); v4.y *= bf2f(g.us[1]);
        v4.z *= bf2f(g.us[2]); v4.w *= bf2f(g.us[3]);
        *(float4*)&out[(rowbase + r) * ZD + cq] = v4;
    }
}

extern "C" void kernel_launch(void* const* d_in, const int* in_sizes, int n_in,
                              void* d_out, int out_size, void* d_ws, size_t ws_size,
                              hipStream_t stream) {
    (void)in_sizes; (void)n_in; (void)out_size; (void)ws_size;
    const float* z   = (const float*)d_in[0];
    const float* nw  = (const float*)d_in[1];
    const float* nb  = (const float*)d_in[2];
    const float* onw = (const float*)d_in[3];
    const float* onb = (const float*)d_in[4];
    const float* aw  = (const float*)d_in[5];
    const float* ab  = (const float*)d_in[6];
    const float* agw = (const float*)d_in[7];
    const float* agb = (const float*)d_in[8];
    const float* gw  = (const float*)d_in[9];
    const float* gb  = (const float*)d_in[10];
    const float* ow  = (const float*)d_in[11];
    const float* ob  = (const float*)d_in[12];

    char* ws = (char*)d_ws;
    ushort* a_t  = (ushort*)ws;                                   // 37,748,736 B
    ushort* gate = (ushort*)(ws + 37748736);                      // 150,994,944 B
    float*  obuf = (float*)(ws + 37748736 + 150994944);           // 75,497,472 B
    ushort* wfrag = (ushort*)obuf;  // aliased: live only k0->k1, k2 clobbers

    k0_wfrag<<<12, 256, 0, stream>>>(aw, agw, gw, wfrag);
    k1_ln_proj<<<LL / 64, 256, 0, stream>>>(z, nw, nb, wfrag, ab, agb, gb,
                                            a_t, gate);
    k2_einsum<<<dim3(12, 12, 32), 256, 0, stream>>>(a_t, obuf);
    k3_out<<<LL / 64, 256, 0, stream>>>(obuf, onw, onb, ow, ob, gate,
                                        (float*)d_out);
}

// Round 6
// 293.524 us; speedup vs baseline: 1.6629x; 1.2453x over previous
//
#include <hip/hip_runtime.h>
#include <math.h>

// TriOut: z[L,L,Z] -> LN -> gated proj to C -> einsum('ilc,jlc->ijc') -> LN(C)
//         -> proj back to Z -> * sigmoid(zn@g_w+g_b)
// L=768, Z=128, C=32.  Output fp32 [L,L,Z].
//
// ws layout:
//   a_t  : bf16 [C][L*L]   ( 37,748,736 B)  a, c-major -> 32 batched A*A^T GEMMs
//   gate : bf16 [L*L][Z]   (150,994,944 B)  sigmoid(zn@g_w + g_b)
//   obuf : fp32 [C][L*L]   ( 75,497,472 B)  einsum result, c-major
//   wfrag: bf16 frag-ordered [12*4][64][8] aliased onto obuf start (48 KB;
//          live during k0..k1, k2 clobbers)

#define LDIM 768
#define LL   (768 * 768)
#define ZD   128
#define CD   32

typedef __bf16 bf16x8 __attribute__((ext_vector_type(8)));
typedef float  f32x4  __attribute__((ext_vector_type(4)));

__device__ __forceinline__ ushort f2bf(float f) {
    __bf16 h = (__bf16)f;                      // RNE convert
    return __builtin_bit_cast(ushort, h);
}
__device__ __forceinline__ float bf2f(ushort u) {
    return __builtin_bit_cast(float, ((unsigned)u) << 16);
}
// fast sigmoid: v_exp_f32 + v_rcp_f32 (~1 ulp fp32 -- far below bf16 rounding)
__device__ __forceinline__ float sigm(float x) {
    return __builtin_amdgcn_rcpf(1.0f + __expf(-x));
}

// ---------------------------------------------------------------------------
// k0: pack [a_w ; ag_w ; g_w] -> bf16 wfrag in MFMA B-FRAGMENT ORDER:
//   frag f = n*4+kk, lane l = fr + 16*hi:
//     wfrag[f*64 + l][j] = W[n*16+fr][kk*32 + hi*8 + j],  j=0..7
// ---------------------------------------------------------------------------
__global__ __launch_bounds__(256) void k0_wfrag(
    const float* __restrict__ aw, const float* __restrict__ agw,
    const float* __restrict__ gw, ushort* __restrict__ wfrag)
{
    const int f = blockIdx.x * 256 + threadIdx.x;     // 3072 frags
    if (f >= 12 * 4 * 64) return;
    const int n4 = f >> 6, lane = f & 63;
    const int n = n4 >> 2, kk = n4 & 3;
    const int fr = lane & 15, hi = lane >> 4;
    const int ch = n * 16 + fr;
    const int k0 = kk * 32 + hi * 8;
    const float* src = (ch < 32) ? (aw + ch * ZD)
                     : (ch < 64) ? (agw + (ch - 32) * ZD)
                                 : (gw + (ch - 64) * ZD);
    union { ushort us[8]; uint4 q; } pk;
    #pragma unroll
    for (int j = 0; j < 8; ++j) pk.us[j] = f2bf(src[k0 + j]);
    *(uint4*)&wfrag[(size_t)f * 8] = pk.q;
}

// ---------------------------------------------------------------------------
// k1 v3: 2304 blocks x 4 chunks of 64 rows.
//   - channel-split: wave w owns 3 n-tiles for ALL 64 rows:
//       w0:{0(a0),2(ag0),4(g0)}  w1:{1(a1),3(ag1),5(g1)}  w2:{6,7,8}  w3:{9,10,11}
//     -> 12 B-frags (48 VGPR) loaded ONCE per block, zero loads in the loop.
//   - z for chunk c+1 prefetched into regs while chunk c computes.
//   - LDS: zn[64][136] (A-operand) + gl[64][136] (gate transpose) = 34.8 KB.
//   - 3 barriers/chunk.
// ---------------------------------------------------------------------------
__global__ __launch_bounds__(256) void k1_ln_proj(
    const float* __restrict__ z, const float* __restrict__ nw, const float* __restrict__ nb,
    const ushort* __restrict__ wfrag,
    const float* __restrict__ ab, const float* __restrict__ agb, const float* __restrict__ gb,
    ushort* __restrict__ a_t, ushort* __restrict__ gate)
{
    __shared__ ushort zn[64][136];
    __shared__ ushort gl[64][136];

    const int tid = threadIdx.x;
    const int lane = tid & 63, wave = tid >> 6;
    const int fr = lane & 15, hi = lane >> 4;

    // owned n-tiles
    const int t0 = (wave < 2) ? wave     : 6 + (wave - 2) * 3;
    const int t1 = (wave < 2) ? wave + 2 : t0 + 1;
    const int t2 = (wave < 2) ? wave + 4 : t0 + 2;

    // B-fragments: loaded once, held in registers (12 x 4 VGPR)
    bf16x8 bv0[4], bv1[4], bv2[4];
    {
        const ushort* wl = wfrag + (size_t)lane * 8;
        #pragma unroll
        for (int kk = 0; kk < 4; ++kk) {
            bv0[kk] = *(const bf16x8*)(wl + (size_t)(t0 * 4 + kk) * 512);
            bv1[kk] = *(const bf16x8*)(wl + (size_t)(t1 * 4 + kk) * 512);
            bv2[kk] = *(const bf16x8*)(wl + (size_t)(t2 * 4 + kk) * 512);
        }
    }

    // biases (per-lane scalars, hoisted)
    float abv = 0.f, agbv = 0.f, gbv0 = 0.f, gbv1 = 0.f, gbv2;
    if (wave < 2) {
        abv  = ab[wave * 16 + fr];
        agbv = agb[wave * 16 + fr];
        gbv2 = gb[t2 * 16 - 64 + fr];
    } else {
        gbv0 = gb[t0 * 16 - 64 + fr];
        gbv1 = gb[t1 * 16 - 64 + fr];
        gbv2 = gb[t2 * 16 - 64 + fr];
    }

    const size_t blockrow = (size_t)blockIdx.x * 256;
    const int lr = tid >> 2, seg = tid & 3;     // LN: 4 threads/row

    float4 zreg[8];
    {
        const float4* zp = (const float4*)(z + (blockrow + lr) * ZD + seg * 32);
        #pragma unroll
        for (int q = 0; q < 8; ++q) zreg[q] = zp[q];
    }

    for (int c = 0; c < 4; ++c) {
        __syncthreads();   // zn/gl safe to rewrite (prev chunk fully consumed)

        // ---- LN from prefetched regs -> zn bf16 ----
        {
            float v[32];
            #pragma unroll
            for (int q = 0; q < 8; ++q) {
                v[q * 4 + 0] = zreg[q].x; v[q * 4 + 1] = zreg[q].y;
                v[q * 4 + 2] = zreg[q].z; v[q * 4 + 3] = zreg[q].w;
            }
            float s = 0.f, ss = 0.f;
            #pragma unroll
            for (int e = 0; e < 32; ++e) { s += v[e]; ss += v[e] * v[e]; }
            s += __shfl_xor(s, 1); ss += __shfl_xor(ss, 1);
            s += __shfl_xor(s, 2); ss += __shfl_xor(ss, 2);
            const float mu  = s * (1.f / 128.f);
            const float var = ss * (1.f / 128.f) - mu * mu;
            const float rs  = rsqrtf(var + 1e-5f);
            union { ushort u[32]; uint4 q4[4]; } pk;
            #pragma unroll
            for (int e = 0; e < 32; ++e) {
                const int k = seg * 32 + e;
                pk.u[e] = f2bf((v[e] - mu) * rs * nw[k] + nb[k]);
            }
            #pragma unroll
            for (int q = 0; q < 4; ++q)
                *(uint4*)&zn[lr][seg * 32 + q * 8] = pk.q4[q];
        }

        // ---- prefetch next chunk's z (regs are dead after the pack) ----
        if (c < 3) {
            const float4* zp = (const float4*)(z + (blockrow + (c + 1) * 64 + lr) * ZD + seg * 32);
            #pragma unroll
            for (int q = 0; q < 8; ++q) zreg[q] = zp[q];
        }
        __syncthreads();   // zn ready

        // ---- MFMA: 4 m-tiles x 3 owned n-tiles x 4 k ----
        f32x4 acc0[4], acc1[4], acc2[4];
        #pragma unroll
        for (int m = 0; m < 4; ++m) {
            acc0[m] = (f32x4){0.f, 0.f, 0.f, 0.f};
            acc1[m] = (f32x4){0.f, 0.f, 0.f, 0.f};
            acc2[m] = (f32x4){0.f, 0.f, 0.f, 0.f};
        }
        #pragma unroll
        for (int m = 0; m < 4; ++m) {
            bf16x8 afm[4];
            #pragma unroll
            for (int kk = 0; kk < 4; ++kk)
                afm[kk] = *(const bf16x8*)&zn[m * 16 + fr][kk * 32 + hi * 8];
            #pragma unroll
            for (int kk = 0; kk < 4; ++kk) {
                acc0[m] = __builtin_amdgcn_mfma_f32_16x16x32_bf16(afm[kk], bv0[kk], acc0[m], 0, 0, 0);
                acc1[m] = __builtin_amdgcn_mfma_f32_16x16x32_bf16(afm[kk], bv1[kk], acc1[m], 0, 0, 0);
                acc2[m] = __builtin_amdgcn_mfma_f32_16x16x32_bf16(afm[kk], bv2[kk], acc2[m], 0, 0, 0);
            }
        }

        // ---- epilogue ----
        const size_t rb = blockrow + (size_t)c * 64;
        if (wave < 2) {
            // a = (a_lin + ab) * sigm(ag_lin + agb) -> a_t c-major
            const int ch = wave * 16 + fr;
            #pragma unroll
            for (int m = 0; m < 4; ++m) {
                union { ushort u[4]; uint2 d; } pk;
                #pragma unroll
                for (int q = 0; q < 4; ++q)
                    pk.u[q] = f2bf((acc0[m][q] + abv) * sigm(acc1[m][q] + agbv));
                *(uint2*)&a_t[(size_t)ch * LL + rb + m * 16 + hi * 4] = pk.d;
            }
            // gate tile t2 -> gl transpose
            const int gch = t2 * 16 - 64 + fr;
            #pragma unroll
            for (int m = 0; m < 4; ++m)
                #pragma unroll
                for (int q = 0; q < 4; ++q)
                    gl[m * 16 + hi * 4 + q][gch] = f2bf(sigm(acc2[m][q] + gbv2));
        } else {
            const int g0 = t0 * 16 - 64 + fr;
            const int g1 = t1 * 16 - 64 + fr;
            const int g2 = t2 * 16 - 64 + fr;
            #pragma unroll
            for (int m = 0; m < 4; ++m)
                #pragma unroll
                for (int q = 0; q < 4; ++q) {
                    const int row = m * 16 + hi * 4 + q;
                    gl[row][g0] = f2bf(sigm(acc0[m][q] + gbv0));
                    gl[row][g1] = f2bf(sigm(acc1[m][q] + gbv1));
                    gl[row][g2] = f2bf(sigm(acc2[m][q] + gbv2));
                }
        }
        __syncthreads();   // gl complete

        // ---- coalesced gate copy-out ----
        #pragma unroll
        for (int it = 0; it < 4; ++it) {
            const int idx = it * 256 + tid;    // 1024 uint4 chunks
            const int r = idx >> 4, cq = idx & 15;
            *(uint4*)&gate[(rb + r) * ZD + cq * 8] = *(const uint4*)&gl[r][cq * 8];
        }
    }
}

// ---------------------------------------------------------------------------
// k2: 32 batched GEMMs  O_c = M_c * M_c^T,  M_c = a_t[c] as [768][768] bf16.
// 64x64 tile, BK=32, 4 waves (each 32x32 quadrant = 2x2 mfma_f32_16x16x32_bf16).
// ---------------------------------------------------------------------------
__global__ __launch_bounds__(256) void k2_einsum(
    const ushort* __restrict__ a_t, float* __restrict__ obuf)
{
    __shared__ ushort As[2][64][32];
    __shared__ ushort Bs[2][64][32];

    const int tid = threadIdx.x;
    const int c  = blockIdx.z;
    const int i0 = blockIdx.y * 64, j0 = blockIdx.x * 64;
    const ushort* base = a_t + (size_t)c * LL;

    const int srow = tid >> 2, scol = (tid & 3) * 8;
    const ushort* gA = base + (size_t)(i0 + srow) * LDIM + scol;
    const ushort* gB = base + (size_t)(j0 + srow) * LDIM + scol;

    const int wave = tid >> 6, lane = tid & 63;
    const int wi = (wave >> 1) * 32, wj = (wave & 1) * 32;
    const int fr = lane & 15, k8 = (lane >> 4) * 8;

    f32x4 acc[2][2];
    #pragma unroll
    for (int m = 0; m < 2; ++m)
        #pragma unroll
        for (int n = 0; n < 2; ++n)
            acc[m][n] = (f32x4){0.f, 0.f, 0.f, 0.f};

    auto stage = [&](int b, int kc) {
        *(uint4*)&As[b][srow][scol] = *(const uint4*)(gA + kc * 32);
        *(uint4*)&Bs[b][srow][scol] = *(const uint4*)(gB + kc * 32);
    };

    stage(0, 0);
    __syncthreads();
    for (int kc = 0; kc < 24; ++kc) {
        const int cur = kc & 1;
        if (kc + 1 < 24) stage(cur ^ 1, kc + 1);

        bf16x8 av[2], bv[2];
        #pragma unroll
        for (int m = 0; m < 2; ++m)
            av[m] = *(const bf16x8*)&As[cur][wi + m * 16 + fr][k8];
        #pragma unroll
        for (int n = 0; n < 2; ++n)
            bv[n] = *(const bf16x8*)&Bs[cur][wj + n * 16 + fr][k8];

        #pragma unroll
        for (int m = 0; m < 2; ++m)
            #pragma unroll
            for (int n = 0; n < 2; ++n)
                acc[m][n] = __builtin_amdgcn_mfma_f32_16x16x32_bf16(
                    av[m], bv[n], acc[m][n], 0, 0, 0);
        __syncthreads();
    }

    float* ob = obuf + (size_t)c * LL;
    #pragma unroll
    for (int m = 0; m < 2; ++m)
        #pragma unroll
        for (int n = 0; n < 2; ++n)
            #pragma unroll
            for (int q = 0; q < 4; ++q) {
                const int row = i0 + wi + m * 16 + (lane >> 4) * 4 + q;
                const int col = j0 + wj + n * 16 + fr;
                ob[(size_t)row * LDIM + col] = acc[m][n][q];
            }
}

// ---------------------------------------------------------------------------
// k3: per 64 flat rows of [L*L, ...]:
//   gather obuf (c-major) -> LDS, LN over C=32 (affine) -> bf16 An[64][36],
//   o_w staged bf16 Bw[128][36]; wave w: rows w*16..+15 x 128 out = 8 MFMA
//   (single k-step, K=32); +o_b -> fp32 Res (aliased over gather buf);
//   final: Res * gate -> out, fully coalesced float4.
// ---------------------------------------------------------------------------
__global__ __launch_bounds__(256) void k3_out(
    const float* __restrict__ obuf,
    const float* __restrict__ onw, const float* __restrict__ onb,
    const float* __restrict__ ow,  const float* __restrict__ obias,
    const ushort* __restrict__ gate, float* __restrict__ out)
{
    __shared__ union { float Ol[64][40]; float Res[64][132]; } u;
    __shared__ ushort An[64][36];
    __shared__ ushort Bw[128][36];

    const int tid = threadIdx.x;
    const size_t rowbase = (size_t)blockIdx.x * 64;

    // ---- gather obuf: wave cg loads channels cg*8..+7 for all 64 rows ----
    {
        const int jj = tid & 63, cg = tid >> 6;
        const size_t off = rowbase + jj;
        #pragma unroll
        for (int cc = 0; cc < 8; ++cc) {
            const int ch = cg * 8 + cc;
            u.Ol[jj][ch] = obuf[(size_t)ch * LL + off];
        }
    }
    // ---- stage o_w -> bf16 Bw: thread t -> row t>>1, 16-ch half t&1 ----
    {
        const int r = tid >> 1, h = tid & 1;
        const float* src = ow + r * CD + h * 16;
        union { ushort us[16]; uint4 q[2]; } pk;
        #pragma unroll
        for (int e = 0; e < 16; ++e) pk.us[e] = f2bf(src[e]);
        *(uint4*)&Bw[r][h * 16]     = pk.q[0];
        *(uint4*)&Bw[r][h * 16 + 8] = pk.q[1];
    }
    __syncthreads();

    // ---- LN over C=32: 4 threads/row, 8 ch each, affine -> bf16 An ----
    {
        const int r = tid >> 2, seg = tid & 3;
        float v[8];
        #pragma unroll
        for (int e = 0; e < 8; ++e) v[e] = u.Ol[r][seg * 8 + e];
        float s = 0.f, ss = 0.f;
        #pragma unroll
        for (int e = 0; e < 8; ++e) { s += v[e]; ss += v[e] * v[e]; }
        s += __shfl_xor(s, 1); ss += __shfl_xor(ss, 1);
        s += __shfl_xor(s, 2); ss += __shfl_xor(ss, 2);
        const float mu  = s * (1.f / 32.f);
        const float var = ss * (1.f / 32.f) - mu * mu;
        const float rs  = rsqrtf(var + 1e-5f);
        union { ushort us[8]; uint4 q; } pk;
        #pragma unroll
        for (int e = 0; e < 8; ++e) {
            const int c = seg * 8 + e;
            pk.us[e] = f2bf((v[e] - mu) * rs * onw[c] + onb[c]);
        }
        *(uint4*)&An[r][seg * 8] = pk.q;
    }
    __syncthreads();   // An/Bw ready; Ol dead beyond this point

    // ---- MFMA: wave w -> rows w*16..+15, 128 outputs, single k-step ----
    const int lane = tid & 63, wave = tid >> 6;
    const int fr = lane & 15, hi = lane >> 4;
    const int wrow = wave * 16;

    const bf16x8 af = *(const bf16x8*)&An[wrow + fr][hi * 8];
    f32x4 acc[8];
    #pragma unroll
    for (int n = 0; n < 8; ++n) {
        const bf16x8 bv = *(const bf16x8*)&Bw[n * 16 + fr][hi * 8];
        acc[n] = __builtin_amdgcn_mfma_f32_16x16x32_bf16(
            af, bv, (f32x4){0.f, 0.f, 0.f, 0.f}, 0, 0, 0);
    }

    // ---- +bias -> Res (aliases dead Ol) ----
    #pragma unroll
    for (int n = 0; n < 8; ++n) {
        const int ch = n * 16 + fr;
        const float obv = obias[ch];
        #pragma unroll
        for (int q = 0; q < 4; ++q)
            u.Res[wrow + hi * 4 + q][ch] = acc[n][q] + obv;
    }
    __syncthreads();

    // ---- Res * gate -> out, coalesced ----
    #pragma unroll
    for (int it = 0; it < 8; ++it) {
        const int idx = it * 256 + tid;          // 2048 float4 chunks
        const int r = idx >> 5, cq = (idx & 31) * 4;
        float4 v4 = *(const float4*)&u.Res[r][cq];
        union { uint2 d; ushort us[4]; } g;
        g.d = *(const uint2*)&gate[(rowbase + r) * ZD + cq];
        v4.x *= bf2f(g.us[0]); v4.y *= bf2f(g.us[1]);
        v4.z *= bf2f(g.us[2]); v4.w *= bf2f(g.us[3]);
        *(float4*)&out[(rowbase + r) * ZD + cq] = v4;
    }
}

extern "C" void kernel_launch(void* const* d_in, const int* in_sizes, int n_in,
                              void* d_out, int out_size, void* d_ws, size_t ws_size,
                              hipStream_t stream) {
    (void)in_sizes; (void)n_in; (void)out_size; (void)ws_size;
    const float* z   = (const float*)d_in[0];
    const float* nw  = (const float*)d_in[1];
    const float* nb  = (const float*)d_in[2];
    const float* onw = (const float*)d_in[3];
    const float* onb = (const float*)d_in[4];
    const float* aw  = (const float*)d_in[5];
    const float* ab  = (const float*)d_in[6];
    const float* agw = (const float*)d_in[7];
    const float* agb = (const float*)d_in[8];
    const float* gw  = (const float*)d_in[9];
    const float* gb  = (const float*)d_in[10];
    const float* ow  = (const float*)d_in[11];
    const float* ob  = (const float*)d_in[12];

    char* ws = (char*)d_ws;
    ushort* a_t  = (ushort*)ws;                                   // 37,748,736 B
    ushort* gate = (ushort*)(ws + 37748736);                      // 150,994,944 B
    float*  obuf = (float*)(ws + 37748736 + 150994944);           // 75,497,472 B
    ushort* wfrag = (ushort*)obuf;  // aliased: live only k0->k1, k2 clobbers

    k0_wfrag<<<12, 256, 0, stream>>>(aw, agw, gw, wfrag);
    k1_ln_proj<<<LL / 256, 256, 0, stream>>>(z, nw, nb, wfrag, ab, agb, gb,
                                             a_t, gate);
    k2_einsum<<<dim3(12, 12, 32), 256, 0, stream>>>(a_t, obuf);
    k3_out<<<LL / 64, 256, 0, stream>>>(obuf, onw, onb, ow, ob, gate,
                                        (float*)d_out);
}

// Round 7
// 287.624 us; speedup vs baseline: 1.6970x; 1.0205x over previous
//
#include <hip/hip_runtime.h>
#include <math.h>

// TriOut: z[L,L,Z] -> LN -> gated proj to C -> einsum('ilc,jlc->ijc') -> LN(C)
//         -> proj back to Z -> * sigmoid(zn@g_w+g_b)
// L=768, Z=128, C=32.  Output fp32 [L,L,Z].
//
// ws layout:
//   a_t  : bf16 [C][L*L]   ( 37,748,736 B)  a, c-major -> 32 batched A*A^T GEMMs
//   gate : bf16 [L*L][Z]   (150,994,944 B)  sigmoid(zn@g_w + g_b)
//   obuf : fp32 [C][L*L]   ( 75,497,472 B)  einsum result, c-major
//   wfrag: bf16 frag-ordered [12*4][64][8] aliased onto obuf start (48 KB;
//          live during k0..k1, k2 clobbers)

#define LDIM 768
#define LL   (768 * 768)
#define ZD   128
#define CD   32

typedef __bf16 bf16x8 __attribute__((ext_vector_type(8)));
typedef float  f32x4  __attribute__((ext_vector_type(4)));

__device__ __forceinline__ ushort f2bf(float f) {
    __bf16 h = (__bf16)f;                      // RNE convert
    return __builtin_bit_cast(ushort, h);
}
__device__ __forceinline__ float bf2f(ushort u) {
    return __builtin_bit_cast(float, ((unsigned)u) << 16);
}
// fast sigmoid: v_exp_f32 + v_rcp_f32 (~1 ulp fp32 -- far below bf16 rounding)
__device__ __forceinline__ float sigm(float x) {
    return __builtin_amdgcn_rcpf(1.0f + __expf(-x));
}

// ---------------------------------------------------------------------------
// k0: pack [a_w ; ag_w ; g_w] -> bf16 wfrag in MFMA B-FRAGMENT ORDER:
//   frag f = n*4+kk, lane l = fr + 16*hi:
//     wfrag[f*64 + l][j] = W[n*16+fr][kk*32 + hi*8 + j],  j=0..7
// ---------------------------------------------------------------------------
__global__ __launch_bounds__(256) void k0_wfrag(
    const float* __restrict__ aw, const float* __restrict__ agw,
    const float* __restrict__ gw, ushort* __restrict__ wfrag)
{
    const int f = blockIdx.x * 256 + threadIdx.x;     // 3072 frags
    if (f >= 12 * 4 * 64) return;
    const int n4 = f >> 6, lane = f & 63;
    const int n = n4 >> 2, kk = n4 & 3;
    const int fr = lane & 15, hi = lane >> 4;
    const int ch = n * 16 + fr;
    const int k0 = kk * 32 + hi * 8;
    const float* src = (ch < 32) ? (aw + ch * ZD)
                     : (ch < 64) ? (agw + (ch - 32) * ZD)
                                 : (gw + (ch - 64) * ZD);
    union { ushort us[8]; uint4 q; } pk;
    #pragma unroll
    for (int j = 0; j < 8; ++j) pk.us[j] = f2bf(src[k0 + j]);
    *(uint4*)&wfrag[(size_t)f * 8] = pk.q;
}

// ---------------------------------------------------------------------------
// k1 v3: 2304 blocks x 4 chunks of 64 rows.
//   - channel-split: wave w owns 3 n-tiles for ALL 64 rows:
//       w0:{0(a0),2(ag0),4(g0)}  w1:{1(a1),3(ag1),5(g1)}  w2:{6,7,8}  w3:{9,10,11}
//     -> 12 B-frags (48 VGPR) loaded ONCE per block, zero loads in the loop.
//   - z for chunk c+1 prefetched into regs while chunk c computes.
//   - LDS: zn[64][136] (A-operand) + gl[64][136] (gate transpose) = 34.8 KB.
// ---------------------------------------------------------------------------
__global__ __launch_bounds__(256) void k1_ln_proj(
    const float* __restrict__ z, const float* __restrict__ nw, const float* __restrict__ nb,
    const ushort* __restrict__ wfrag,
    const float* __restrict__ ab, const float* __restrict__ agb, const float* __restrict__ gb,
    ushort* __restrict__ a_t, ushort* __restrict__ gate)
{
    __shared__ ushort zn[64][136];
    __shared__ ushort gl[64][136];

    const int tid = threadIdx.x;
    const int lane = tid & 63, wave = tid >> 6;
    const int fr = lane & 15, hi = lane >> 4;

    // owned n-tiles
    const int t0 = (wave < 2) ? wave     : 6 + (wave - 2) * 3;
    const int t1 = (wave < 2) ? wave + 2 : t0 + 1;
    const int t2 = (wave < 2) ? wave + 4 : t0 + 2;

    // B-fragments: loaded once, held in registers (12 x 4 VGPR)
    bf16x8 bv0[4], bv1[4], bv2[4];
    {
        const ushort* wl = wfrag + (size_t)lane * 8;
        #pragma unroll
        for (int kk = 0; kk < 4; ++kk) {
            bv0[kk] = *(const bf16x8*)(wl + (size_t)(t0 * 4 + kk) * 512);
            bv1[kk] = *(const bf16x8*)(wl + (size_t)(t1 * 4 + kk) * 512);
            bv2[kk] = *(const bf16x8*)(wl + (size_t)(t2 * 4 + kk) * 512);
        }
    }

    // biases (per-lane scalars, hoisted)
    float abv = 0.f, agbv = 0.f, gbv0 = 0.f, gbv1 = 0.f, gbv2;
    if (wave < 2) {
        abv  = ab[wave * 16 + fr];
        agbv = agb[wave * 16 + fr];
        gbv2 = gb[t2 * 16 - 64 + fr];
    } else {
        gbv0 = gb[t0 * 16 - 64 + fr];
        gbv1 = gb[t1 * 16 - 64 + fr];
        gbv2 = gb[t2 * 16 - 64 + fr];
    }

    const size_t blockrow = (size_t)blockIdx.x * 256;
    const int lr = tid >> 2, seg = tid & 3;     // LN: 4 threads/row

    float4 zreg[8];
    {
        const float4* zp = (const float4*)(z + (blockrow + lr) * ZD + seg * 32);
        #pragma unroll
        for (int q = 0; q < 8; ++q) zreg[q] = zp[q];
    }

    for (int c = 0; c < 4; ++c) {
        __syncthreads();   // zn/gl safe to rewrite (prev chunk fully consumed)

        // ---- LN from prefetched regs -> zn bf16 ----
        {
            float v[32];
            #pragma unroll
            for (int q = 0; q < 8; ++q) {
                v[q * 4 + 0] = zreg[q].x; v[q * 4 + 1] = zreg[q].y;
                v[q * 4 + 2] = zreg[q].z; v[q * 4 + 3] = zreg[q].w;
            }
            float s = 0.f, ss = 0.f;
            #pragma unroll
            for (int e = 0; e < 32; ++e) { s += v[e]; ss += v[e] * v[e]; }
            s += __shfl_xor(s, 1); ss += __shfl_xor(ss, 1);
            s += __shfl_xor(s, 2); ss += __shfl_xor(ss, 2);
            const float mu  = s * (1.f / 128.f);
            const float var = ss * (1.f / 128.f) - mu * mu;
            const float rs  = rsqrtf(var + 1e-5f);
            union { ushort u[32]; uint4 q4[4]; } pk;
            #pragma unroll
            for (int e = 0; e < 32; ++e) {
                const int k = seg * 32 + e;
                pk.u[e] = f2bf((v[e] - mu) * rs * nw[k] + nb[k]);
            }
            #pragma unroll
            for (int q = 0; q < 4; ++q)
                *(uint4*)&zn[lr][seg * 32 + q * 8] = pk.q4[q];
        }

        // ---- prefetch next chunk's z (regs are dead after the pack) ----
        if (c < 3) {
            const float4* zp = (const float4*)(z + (blockrow + (c + 1) * 64 + lr) * ZD + seg * 32);
            #pragma unroll
            for (int q = 0; q < 8; ++q) zreg[q] = zp[q];
        }
        __syncthreads();   // zn ready

        // ---- MFMA: 4 m-tiles x 3 owned n-tiles x 4 k ----
        f32x4 acc0[4], acc1[4], acc2[4];
        #pragma unroll
        for (int m = 0; m < 4; ++m) {
            acc0[m] = (f32x4){0.f, 0.f, 0.f, 0.f};
            acc1[m] = (f32x4){0.f, 0.f, 0.f, 0.f};
            acc2[m] = (f32x4){0.f, 0.f, 0.f, 0.f};
        }
        #pragma unroll
        for (int m = 0; m < 4; ++m) {
            bf16x8 afm[4];
            #pragma unroll
            for (int kk = 0; kk < 4; ++kk)
                afm[kk] = *(const bf16x8*)&zn[m * 16 + fr][kk * 32 + hi * 8];
            #pragma unroll
            for (int kk = 0; kk < 4; ++kk) {
                acc0[m] = __builtin_amdgcn_mfma_f32_16x16x32_bf16(afm[kk], bv0[kk], acc0[m], 0, 0, 0);
                acc1[m] = __builtin_amdgcn_mfma_f32_16x16x32_bf16(afm[kk], bv1[kk], acc1[m], 0, 0, 0);
                acc2[m] = __builtin_amdgcn_mfma_f32_16x16x32_bf16(afm[kk], bv2[kk], acc2[m], 0, 0, 0);
            }
        }

        // ---- epilogue ----
        const size_t rb = blockrow + (size_t)c * 64;
        if (wave < 2) {
            // a = (a_lin + ab) * sigm(ag_lin + agb) -> a_t c-major
            const int ch = wave * 16 + fr;
            #pragma unroll
            for (int m = 0; m < 4; ++m) {
                union { ushort u[4]; uint2 d; } pk;
                #pragma unroll
                for (int q = 0; q < 4; ++q)
                    pk.u[q] = f2bf((acc0[m][q] + abv) * sigm(acc1[m][q] + agbv));
                *(uint2*)&a_t[(size_t)ch * LL + rb + m * 16 + hi * 4] = pk.d;
            }
            // gate tile t2 -> gl transpose
            const int gch = t2 * 16 - 64 + fr;
            #pragma unroll
            for (int m = 0; m < 4; ++m)
                #pragma unroll
                for (int q = 0; q < 4; ++q)
                    gl[m * 16 + hi * 4 + q][gch] = f2bf(sigm(acc2[m][q] + gbv2));
        } else {
            const int g0 = t0 * 16 - 64 + fr;
            const int g1 = t1 * 16 - 64 + fr;
            const int g2 = t2 * 16 - 64 + fr;
            #pragma unroll
            for (int m = 0; m < 4; ++m)
                #pragma unroll
                for (int q = 0; q < 4; ++q) {
                    const int row = m * 16 + hi * 4 + q;
                    gl[row][g0] = f2bf(sigm(acc0[m][q] + gbv0));
                    gl[row][g1] = f2bf(sigm(acc1[m][q] + gbv1));
                    gl[row][g2] = f2bf(sigm(acc2[m][q] + gbv2));
                }
        }
        __syncthreads();   // gl complete

        // ---- coalesced gate copy-out ----
        #pragma unroll
        for (int it = 0; it < 4; ++it) {
            const int idx = it * 256 + tid;    // 1024 uint4 chunks
            const int r = idx >> 4, cq = idx & 15;
            *(uint4*)&gate[(rb + r) * ZD + cq * 8] = *(const uint4*)&gl[r][cq * 8];
        }
    }
}

// ---------------------------------------------------------------------------
// k2 v2: 32 batched SYMMETRIC GEMMs  O_c = M_c * M_c^T  (o[i,j,c]==o[j,i,c]).
//   Only the 78 upper-triangular 64x64 tile-pairs (bi<=bj) are computed;
//   off-diagonal tiles are written twice (normal + transposed mirror, both
//   64B-granular).  Staging via global_load_lds (linear dest = tid*16B).
// ---------------------------------------------------------------------------
__global__ __launch_bounds__(256) void k2_einsum(
    const ushort* __restrict__ a_t, float* __restrict__ obuf)
{
    __shared__ ushort As[2][64][32];
    __shared__ ushort Bs[2][64][32];

    const int tid = threadIdx.x;
    const int c = blockIdx.y;
    // triangular decode: p -> (bi, bj) with bi <= bj (12 tiles/side, 78 pairs)
    int p = blockIdx.x, bi = 0;
    while (p >= 12 - bi) { p -= 12 - bi; ++bi; }
    const int bj = bi + p;
    const int i0 = bi * 64, j0 = bj * 64;
    const ushort* base = a_t + (size_t)c * LL;

    const int srow = tid >> 2, scol = (tid & 3) * 8;
    const ushort* gA = base + (size_t)(i0 + srow) * LDIM + scol;
    const ushort* gB = base + (size_t)(j0 + srow) * LDIM + scol;

    const int wave = tid >> 6, lane = tid & 63;
    const int wi = (wave >> 1) * 32, wj = (wave & 1) * 32;
    const int fr = lane & 15, k8 = (lane >> 4) * 8;

    f32x4 acc[2][2];
    #pragma unroll
    for (int m = 0; m < 2; ++m)
        #pragma unroll
        for (int n = 0; n < 2; ++n)
            acc[m][n] = (f32x4){0.f, 0.f, 0.f, 0.f};

    // stage k-chunk kc into buffer b: dest is linear (tid*16B from As[b] base)
    // -> exactly the wave-uniform-base + lane*16 pattern global_load_lds needs
    auto stage = [&](int b, int kc) {
        __builtin_amdgcn_global_load_lds(
            (const uint*)(gA + kc * 32), (uint*)&As[b][srow][scol], 16, 0, 0);
        __builtin_amdgcn_global_load_lds(
            (const uint*)(gB + kc * 32), (uint*)&Bs[b][srow][scol], 16, 0, 0);
    };

    stage(0, 0);
    __syncthreads();
    for (int kc = 0; kc < 24; ++kc) {
        const int cur = kc & 1;
        if (kc + 1 < 24) stage(cur ^ 1, kc + 1);

        bf16x8 av[2], bv[2];
        #pragma unroll
        for (int m = 0; m < 2; ++m)
            av[m] = *(const bf16x8*)&As[cur][wi + m * 16 + fr][k8];
        #pragma unroll
        for (int n = 0; n < 2; ++n)
            bv[n] = *(const bf16x8*)&Bs[cur][wj + n * 16 + fr][k8];

        #pragma unroll
        for (int m = 0; m < 2; ++m)
            #pragma unroll
            for (int n = 0; n < 2; ++n)
                acc[m][n] = __builtin_amdgcn_mfma_f32_16x16x32_bf16(
                    av[m], bv[n], acc[m][n], 0, 0, 0);
        __syncthreads();
    }

    float* ob = obuf + (size_t)c * LL;
    #pragma unroll
    for (int m = 0; m < 2; ++m)
        #pragma unroll
        for (int n = 0; n < 2; ++n) {
            // normal tile write: T[r][c'] -> ob[i0+r][j0+c']
            #pragma unroll
            for (int q = 0; q < 4; ++q) {
                const int row = i0 + wi + m * 16 + (lane >> 4) * 4 + q;
                const int col = j0 + wj + n * 16 + fr;
                ob[(size_t)row * LDIM + col] = acc[m][n][q];
            }
            // mirror write: ob[j0+c'][i0+r] = T[r][c'] (4 consecutive r -> float4)
            if (bi != bj) {
                const int mrow = j0 + wj + n * 16 + fr;
                const int mcol = i0 + wi + m * 16 + (lane >> 4) * 4;
                float4 w;
                w.x = acc[m][n][0]; w.y = acc[m][n][1];
                w.z = acc[m][n][2]; w.w = acc[m][n][3];
                *(float4*)&ob[(size_t)mrow * LDIM + mcol] = w;
            }
        }
}

// ---------------------------------------------------------------------------
// k3: per 64 flat rows of [L*L, ...]:
//   gather obuf (c-major) -> LDS, LN over C=32 (affine) -> bf16 An[64][36],
//   o_w staged bf16 Bw[128][36]; wave w: rows w*16..+15 x 128 out = 8 MFMA
//   (single k-step, K=32); +o_b -> fp32 Res (aliased over gather buf);
//   final: Res * gate -> out, fully coalesced float4.
// ---------------------------------------------------------------------------
__global__ __launch_bounds__(256) void k3_out(
    const float* __restrict__ obuf,
    const float* __restrict__ onw, const float* __restrict__ onb,
    const float* __restrict__ ow,  const float* __restrict__ obias,
    const ushort* __restrict__ gate, float* __restrict__ out)
{
    __shared__ union { float Ol[64][40]; float Res[64][132]; } u;
    __shared__ ushort An[64][36];
    __shared__ ushort Bw[128][36];

    const int tid = threadIdx.x;
    const size_t rowbase = (size_t)blockIdx.x * 64;

    // ---- gather obuf: wave cg loads channels cg*8..+7 for all 64 rows ----
    {
        const int jj = tid & 63, cg = tid >> 6;
        const size_t off = rowbase + jj;
        #pragma unroll
        for (int cc = 0; cc < 8; ++cc) {
            const int ch = cg * 8 + cc;
            u.Ol[jj][ch] = obuf[(size_t)ch * LL + off];
        }
    }
    // ---- stage o_w -> bf16 Bw: thread t -> row t>>1, 16-ch half t&1 ----
    {
        const int r = tid >> 1, h = tid & 1;
        const float* src = ow + r * CD + h * 16;
        union { ushort us[16]; uint4 q[2]; } pk;
        #pragma unroll
        for (int e = 0; e < 16; ++e) pk.us[e] = f2bf(src[e]);
        *(uint4*)&Bw[r][h * 16]     = pk.q[0];
        *(uint4*)&Bw[r][h * 16 + 8] = pk.q[1];
    }
    __syncthreads();

    // ---- LN over C=32: 4 threads/row, 8 ch each, affine -> bf16 An ----
    {
        const int r = tid >> 2, seg = tid & 3;
        float v[8];
        #pragma unroll
        for (int e = 0; e < 8; ++e) v[e] = u.Ol[r][seg * 8 + e];
        float s = 0.f, ss = 0.f;
        #pragma unroll
        for (int e = 0; e < 8; ++e) { s += v[e]; ss += v[e] * v[e]; }
        s += __shfl_xor(s, 1); ss += __shfl_xor(ss, 1);
        s += __shfl_xor(s, 2); ss += __shfl_xor(ss, 2);
        const float mu  = s * (1.f / 32.f);
        const float var = ss * (1.f / 32.f) - mu * mu;
        const float rs  = rsqrtf(var + 1e-5f);
        union { ushort us[8]; uint4 q; } pk;
        #pragma unroll
        for (int e = 0; e < 8; ++e) {
            const int c = seg * 8 + e;
            pk.us[e] = f2bf((v[e] - mu) * rs * onw[c] + onb[c]);
        }
        *(uint4*)&An[r][seg * 8] = pk.q;
    }
    __syncthreads();   // An/Bw ready; Ol dead beyond this point

    // ---- MFMA: wave w -> rows w*16..+15, 128 outputs, single k-step ----
    const int lane = tid & 63, wave = tid >> 6;
    const int fr = lane & 15, hi = lane >> 4;
    const int wrow = wave * 16;

    const bf16x8 af = *(const bf16x8*)&An[wrow + fr][hi * 8];
    f32x4 acc[8];
    #pragma unroll
    for (int n = 0; n < 8; ++n) {
        const bf16x8 bv = *(const bf16x8*)&Bw[n * 16 + fr][hi * 8];
        acc[n] = __builtin_amdgcn_mfma_f32_16x16x32_bf16(
            af, bv, (f32x4){0.f, 0.f, 0.f, 0.f}, 0, 0, 0);
    }

    // ---- +bias -> Res (aliases dead Ol) ----
    #pragma unroll
    for (int n = 0; n < 8; ++n) {
        const int ch = n * 16 + fr;
        const float obv = obias[ch];
        #pragma unroll
        for (int q = 0; q < 4; ++q)
            u.Res[wrow + hi * 4 + q][ch] = acc[n][q] + obv;
    }
    __syncthreads();

    // ---- Res * gate -> out, coalesced ----
    #pragma unroll
    for (int it = 0; it < 8; ++it) {
        const int idx = it * 256 + tid;          // 2048 float4 chunks
        const int r = idx >> 5, cq = (idx & 31) * 4;
        float4 v4 = *(const float4*)&u.Res[r][cq];
        union { uint2 d; ushort us[4]; } g;
        g.d = *(const uint2*)&gate[(rowbase + r) * ZD + cq];
        v4.x *= bf2f(g.us[0]); v4.y *= bf2f(g.us[1]);
        v4.z *= bf2f(g.us[2]); v4.w *= bf2f(g.us[3]);
        *(float4*)&out[(rowbase + r) * ZD + cq] = v4;
    }
}

extern "C" void kernel_launch(void* const* d_in, const int* in_sizes, int n_in,
                              void* d_out, int out_size, void* d_ws, size_t ws_size,
                              hipStream_t stream) {
    (void)in_sizes; (void)n_in; (void)out_size; (void)ws_size;
    const float* z   = (const float*)d_in[0];
    const float* nw  = (const float*)d_in[1];
    const float* nb  = (const float*)d_in[2];
    const float* onw = (const float*)d_in[3];
    const float* onb = (const float*)d_in[4];
    const float* aw  = (const float*)d_in[5];
    const float* ab  = (const float*)d_in[6];
    const float* agw = (const float*)d_in[7];
    const float* agb = (const float*)d_in[8];
    const float* gw  = (const float*)d_in[9];
    const float* gb  = (const float*)d_in[10];
    const float* ow  = (const float*)d_in[11];
    const float* ob  = (const float*)d_in[12];

    char* ws = (char*)d_ws;
    ushort* a_t  = (ushort*)ws;                                   // 37,748,736 B
    ushort* gate = (ushort*)(ws + 37748736);                      // 150,994,944 B
    float*  obuf = (float*)(ws + 37748736 + 150994944);           // 75,497,472 B
    ushort* wfrag = (ushort*)obuf;  // aliased: live only k0->k1, k2 clobbers

    k0_wfrag<<<12, 256, 0, stream>>>(aw, agw, gw, wfrag);
    k1_ln_proj<<<LL / 256, 256, 0, stream>>>(z, nw, nb, wfrag, ab, agb, gb,
                                             a_t, gate);
    k2_einsum<<<dim3(78, 32), 256, 0, stream>>>(a_t, obuf);
    k3_out<<<LL / 64, 256, 0, stream>>>(obuf, onw, onb, ow, ob, gate,
                                        (float*)d_out);
}